// Round 7
// baseline (415.925 us; speedup 1.0000x reference)
//
#include <hip/hip_runtime.h>
#include <stdint.h>

#define IN_F  4096
#define OUT_F 4096

typedef __attribute__((ext_vector_type(8))) short bf16x8;
typedef __attribute__((ext_vector_type(4))) float f32x4;
typedef __attribute__((ext_vector_type(8))) unsigned short u16x8;

__device__ __forceinline__ unsigned short f2bf(float f) {
  union { float f; unsigned int u; } v; v.f = f;
  return (unsigned short)((v.u + 0x7FFFu + ((v.u >> 16) & 1u)) >> 16);
}

__device__ __forceinline__ void gload_lds16(void* lds, const void* g) {
  __builtin_amdgcn_global_load_lds((const __attribute__((address_space(1))) void*)g,
                                   (__attribute__((address_space(3))) void*)lds,
                                   16u, 0, 0u);
}

// ---------------- prep kernels ----------------

__global__ void cvt_x_kernel(const float* __restrict__ x,
                             unsigned short* __restrict__ o, long n8) {
  long i = (long)blockIdx.x * blockDim.x + threadIdx.x;
  long stride = (long)gridDim.x * blockDim.x;
  for (; i < n8; i += stride) {
    const float4* p = (const float4*)(x + i * 8);
    float4 a = p[0], b = p[1];
    u16x8 r;
    r[0] = f2bf(a.x); r[1] = f2bf(a.y); r[2] = f2bf(a.z); r[3] = f2bf(a.w);
    r[4] = f2bf(b.x); r[5] = f2bf(b.y); r[6] = f2bf(b.z); r[7] = f2bf(b.w);
    *(u16x8*)(o + i * 8) = r;
  }
}

// packed_weight arrives as int32 (harness widens uint8 -> int).
__global__ void dequant_w_kernel(const int* __restrict__ pw,
                                 const float* __restrict__ sp,
                                 const float* __restrict__ zpp,
                                 unsigned short* __restrict__ W) {
  const float scale = *sp, zp = *zpp;
  int i = blockIdx.x * blockDim.x + threadIdx.x;
  const int total = (OUT_F / 2) * (IN_F / 8);
  if (i >= total) return;
  int r = i / (IN_F / 8);
  int c = (i - r * (IN_F / 8)) * 8;
  const int* src = pw + (size_t)r * IN_F + c;
  int4 p0 = *(const int4*)(src);
  int4 p1 = *(const int4*)(src + 4);
  int bytes[8] = { p0.x, p0.y, p0.z, p0.w, p1.x, p1.y, p1.z, p1.w };
  u16x8 lo, hi;
#pragma unroll
  for (int j = 0; j < 8; ++j) {
    unsigned int b = (unsigned int)bytes[j] & 0xFFu;
    lo[j] = f2bf(scale * ((float)(b & 15u) - zp));
    hi[j] = f2bf(scale * ((float)(b >> 4) - zp));
  }
  *(u16x8*)(W + (size_t)(2 * r) * IN_F + c) = lo;
  *(u16x8*)(W + (size_t)(2 * r + 1) * IN_F + c) = hi;
}

// ============ 256x256 BK=32 pipelined GEMM (all-pre-zone fragment reads) ====
// 512 thr = 8 waves (2m x 4n); wave owns 128x64. 2 LDS bufs x 32K-step.
// Quadrant order per tile: (A0,B0)(A0,B1)(A1,B1)(A1,B0); A halves used in
// consecutive phases -> 2 A slots; B halves non-consecutive -> 4 B slots.
// Every fragment read is PRE-zone, consumed 1-3 phases later (DS service
// overlaps MFMA via compiler counted-lgkm). Stages: 1 gload/thread/phase:
//   P1:bufO.Ah1(T+1) P2:E.Bh0(T+2) P3:E.Bh1 P4:E.Ah0 P5:E.Ah1
//   P6:O.Bh0(T+3) P7:O.Bh1 P8:O.Ah0
// Verified: per-region read->stage >=2 barriers; stage->read flight 5-7 ph;
// per-phase VM vector [2,2,3,2,2,2,3,2] satisfies BOTH own-wave and
// other-wave (barrier-horizon) constraints for all 8 regions; prologue and
// tail enumerated. Swizzle: chunk' = chunk ^ (row&3), both-sides involution.

#define BAR()   __builtin_amdgcn_s_barrier()
#define SB0()   __builtin_amdgcn_sched_barrier(0)
#define FENCE() asm volatile("" ::: "memory")
#define VM(n)   asm volatile("s_waitcnt vmcnt(" #n ")" ::: "memory")

__global__ __launch_bounds__(512, 2)
void gemm256_kernel(const unsigned short* __restrict__ A,
                    const unsigned short* __restrict__ B,
                    const float* __restrict__ bias,
                    float* __restrict__ C, int M, int N, int K)
{
  __shared__ unsigned short sA[16384];   // [buf][half][128 rows][32] = 32 KiB
  __shared__ unsigned short sB[16384];

  const int tid  = threadIdx.x;
  const int lane = tid & 63;
  const int wid  = tid >> 6;          // 0..7
  const int wm   = wid >> 2;          // 0..1
  const int wn   = wid & 3;           // 0..3

  // T1: XCD-aware bijective swizzle (grid 512 = 8*64)
  const int cpx = gridDim.x >> 3;
  const int swz = ((int)blockIdx.x & 7) * cpx + ((int)blockIdx.x >> 3);
  const int ntn = N >> 8;
  const int tm = swz / ntn, tn = swz - tm * ntn;
  const int row0 = tm << 8, col0 = tn << 8;

  const int lrow  = lane & 15;
  const int ko4   = lane >> 4;                  // 0..3 k-chunk
  const int kswz8 = ((ko4 ^ (lrow & 3)) << 3);  // swizzled chunk offset, elems

  // staging: thread t -> local row t>>2, dest chunk t&3 holds global chunk
  // (t&3)^(row&3)  (involution with the read-side XOR)
  const int srow   = tid >> 2;                  // 0..127
  const int schunk = (tid & 3) ^ (srow & 3);

  f32x4 acc[8][4];
#pragma unroll
  for (int m = 0; m < 8; ++m)
#pragma unroll
    for (int n = 0; n < 4; ++n)
#pragma unroll
      for (int j = 0; j < 4; ++j) acc[m][n][j] = 0.0f;

  bf16x8 sa0[4], sa1[4];               // A slots (one 32-K fragment each)
  bf16x8 u0[2], u1[2], u2[2], u3[2];   // B slots

  // one 8 KiB unit per thread-gload: arr[buf][half] <- G rows half*128..+127, k kt*32..
#define STAGE(arr, buf, half, gbase, kt) do {                                 \
    gload_lds16(arr + (buf)*8192 + (half)*4096 + tid*8,                       \
        (gbase) + (size_t)((half)*128 + srow) * K + (kt)*32 + schunk*8);      \
  } while (0)

#define LDA_(dst, buf, mh) do {                                               \
    _Pragma("unroll")                                                         \
    for (int m2 = 0; m2 < 4; ++m2) {                                          \
      const int off_ = (buf)*8192 + wm*4096 +                                 \
          (((mh)*64 + m2*16 + lrow) << 5) + kswz8;                            \
      dst[m2] = *(const bf16x8*)(sA + off_);                                  \
    } } while (0)

#define LDB_(dst, buf, nh) do {                                               \
    _Pragma("unroll")                                                         \
    for (int n2 = 0; n2 < 2; ++n2) {                                          \
      const int off_ = (buf)*8192 + (wn >> 1)*4096 +                          \
          ((((wn & 1)*64 + (nh)*32 + n2*16 + lrow)) << 5) + kswz8;            \
      dst[n2] = *(const bf16x8*)(sB + off_);                                  \
    } } while (0)

#define MFMA_P(asrc, bsrc, MH, NH) do {                                       \
    __builtin_amdgcn_s_setprio(1);                                            \
    _Pragma("unroll")                                                         \
    for (int m2 = 0; m2 < 4; ++m2)                                            \
      _Pragma("unroll")                                                       \
      for (int n2 = 0; n2 < 2; ++n2)                                          \
        acc[(MH)*4+m2][(NH)*2+n2] = __builtin_amdgcn_mfma_f32_16x16x32_bf16(  \
            asrc[m2], bsrc[n2], acc[(MH)*4+m2][(NH)*2+n2], 0, 0, 0);          \
    __builtin_amdgcn_s_setprio(0);                                            \
  } while (0)

  const unsigned short* Ag = A + (size_t)row0 * K;
  const unsigned short* Bg = B + (size_t)col0 * K;

  // ---- prologue: 7 stages in steady slot order (P2..P8 of virtual prev) ----
  STAGE(sB, 0, 0, Bg, 0);   // #1 E.Bh0(0)
  STAGE(sB, 0, 1, Bg, 0);   // #2 E.Bh1(0)
  STAGE(sA, 0, 0, Ag, 0);   // #3 E.Ah0(0)
  STAGE(sA, 0, 1, Ag, 0);   // #4 E.Ah1(0)
  STAGE(sB, 1, 0, Bg, 1);   // #5 O.Bh0(1)
  STAGE(sB, 1, 1, Bg, 1);   // #6 O.Bh1(1)
  STAGE(sA, 1, 0, Ag, 1);   // #7 O.Ah0(1)
  SB0(); VM(4); SB0();      // #1..#3 landed
  BAR();
  LDA_(sa0, 0, 0);          // A0(0)
  LDB_(u0, 0, 0);           // B0(0)
  asm volatile("s_waitcnt lgkmcnt(0)" ::: "memory");
  SB0(); BAR(); FENCE();

  const int nkt = K >> 5;               // 128 K-tiles of 32
  const int nit = nkt >> 1;             // 64 iterations
  for (int it = 0; it < nit; ++it) {
    const int T   = 2 * it;
    const int t1  = T + 1;                            // <= nkt-1 always
    const int ktE = (T + 2 < nkt) ? T + 2 : nkt - 1;  // clamped stages land in
    const int ktO = (T + 3 < nkt) ? T + 3 : nkt - 1;  // dead/idempotent regions
    // P1: MFMA(A0,B0)T; pre: B1(T)->u1; stage O.Ah1(T+1)
    VM(2); SB0();
    LDB_(u1, 0, 1);
    STAGE(sA, 1, 1, Ag, t1);
    SB0(); BAR();
    MFMA_P(sa0, u0, 0, 0);
    SB0(); BAR(); FENCE();
    // P2: MFMA(A0,B1)T; pre: A1(T)->sa1; stage E.Bh0(T+2)
    VM(2); SB0();
    LDA_(sa1, 0, 1);
    STAGE(sB, 0, 0, Bg, ktE);
    SB0(); BAR();
    MFMA_P(sa0, u1, 0, 1);
    SB0(); BAR(); FENCE();
    // P3: MFMA(A1,B1)T; pre: B0(T+1)->u2; stage E.Bh1(T+2)
    VM(3); SB0();
    LDB_(u2, 1, 0);
    STAGE(sB, 0, 1, Bg, ktE);
    SB0(); BAR();
    MFMA_P(sa1, u1, 1, 1);
    SB0(); BAR(); FENCE();
    // P4: MFMA(A1,B0)T; pre: A0(T+1)->sa0; stage E.Ah0(T+2)
    VM(2); SB0();
    LDA_(sa0, 1, 0);
    STAGE(sA, 0, 0, Ag, ktE);
    SB0(); BAR();
    MFMA_P(sa1, u0, 1, 0);
    SB0(); BAR(); FENCE();
    // P5: MFMA(A0,B0)T+1; pre: B1(T+1)->u3; stage E.Ah1(T+2)
    VM(2); SB0();
    LDB_(u3, 1, 1);
    STAGE(sA, 0, 1, Ag, ktE);
    SB0(); BAR();
    MFMA_P(sa0, u2, 0, 0);
    SB0(); BAR(); FENCE();
    // P6: MFMA(A0,B1)T+1; pre: A1(T+1)->sa1; stage O.Bh0(T+3)
    VM(2); SB0();
    LDA_(sa1, 1, 1);
    STAGE(sB, 1, 0, Bg, ktO);
    SB0(); BAR();
    MFMA_P(sa0, u3, 0, 1);
    SB0(); BAR(); FENCE();
    // P7: MFMA(A1,B1)T+1; pre: B0(T+2)->u0; stage O.Bh1(T+3)
    VM(3); SB0();
    LDB_(u0, 0, 0);
    STAGE(sB, 1, 1, Bg, ktO);
    SB0(); BAR();
    MFMA_P(sa1, u3, 1, 1);
    SB0(); BAR(); FENCE();
    // P8: MFMA(A1,B0)T+1; pre: A0(T+2)->sa0; stage O.Ah0(T+3)
    VM(2); SB0();
    LDA_(sa0, 0, 0);
    STAGE(sA, 1, 0, Ag, ktO);
    SB0(); BAR();
    MFMA_P(sa1, u2, 1, 0);
    SB0(); BAR(); FENCE();
  }

  asm volatile("s_waitcnt vmcnt(0)" ::: "memory");  // drain trailing stages

  // ---- epilogue ----
#pragma unroll
  for (int n = 0; n < 4; ++n) {
    const int col = col0 + wn * 64 + n * 16 + lrow;
    const float bv = bias[col];
#pragma unroll
    for (int m = 0; m < 8; ++m) {
      const int row = row0 + wm * 128 + m * 16 + ko4 * 4;
      const f32x4 v = acc[m][n];
#pragma unroll
      for (int j = 0; j < 4; ++j)
        C[(size_t)(row + j) * N + col] = v[j] + bv;
    }
  }
#undef STAGE
#undef LDA_
#undef LDB_
#undef MFMA_P
}

// ---------------- fallback 128x128 GEMM (correctness safety net) ----------

template <bool XB16>
__global__ __launch_bounds__(256)
void gemm_kernel(const unsigned short* __restrict__ Abf,
                 const float* __restrict__ Af32,
                 const unsigned short* __restrict__ Bbf,
                 const float* __restrict__ bias,
                 float* __restrict__ C, int M, int N, int K)
{
  __shared__ unsigned short sA[128 * 64];
  __shared__ unsigned short sB[128 * 64];
  const int tid  = threadIdx.x;
  const int lane = tid & 63;
  const int wid  = tid >> 6;
  const int wm = wid >> 1, wn = wid & 1;
  const int ntn = N / 128;
  const int tm = blockIdx.x / ntn, tn = blockIdx.x - tm * ntn;
  const int row0 = tm * 128, col0 = tn * 128;

  f32x4 acc[4][4];
#pragma unroll
  for (int m = 0; m < 4; ++m)
#pragma unroll
    for (int n = 0; n < 4; ++n)
#pragma unroll
      for (int j = 0; j < 4; ++j) acc[m][n][j] = 0.0f;

  const int lrow = lane & 15;
  const int lko  = (lane >> 4) * 8;

  for (int k0 = 0; k0 < K; k0 += 64) {
    if (XB16) {
#pragma unroll
      for (int i = 0; i < 4; ++i) {
        const int wbase = i * 256 + (wid << 6);
        const int c = wbase + lane;
        const int r = c >> 3, ce = (c & 7) * 8;
        gload_lds16(sA + (size_t)wbase * 8, Abf + (size_t)(row0 + r) * K + k0 + ce);
      }
    } else {
#pragma unroll
      for (int i = 0; i < 4; ++i) {
        const int c = i * 256 + tid;
        const int r = c >> 3, ce = (c & 7) * 8;
        const float4* p = (const float4*)(Af32 + (size_t)(row0 + r) * K + k0 + ce);
        float4 a = p[0], b = p[1];
        u16x8 v;
        v[0] = f2bf(a.x); v[1] = f2bf(a.y); v[2] = f2bf(a.z); v[3] = f2bf(a.w);
        v[4] = f2bf(b.x); v[5] = f2bf(b.y); v[6] = f2bf(b.z); v[7] = f2bf(b.w);
        *(u16x8*)(sA + c * 8) = v;
      }
    }
#pragma unroll
    for (int i = 0; i < 4; ++i) {
      const int wbase = i * 256 + (wid << 6);
      const int c = wbase + lane;
      const int r = c >> 3, ce = (c & 7) * 8;
      gload_lds16(sB + (size_t)wbase * 8, Bbf + (size_t)(col0 + r) * K + k0 + ce);
    }
    __syncthreads();
    bf16x8 af[4][2], bfr[4][2];
#pragma unroll
    for (int m = 0; m < 4; ++m) {
      const int r = wm * 64 + m * 16 + lrow;
#pragma unroll
      for (int kk = 0; kk < 2; ++kk)
        af[m][kk] = *(const bf16x8*)(sA + r * 64 + kk * 32 + lko);
    }
#pragma unroll
    for (int n = 0; n < 4; ++n) {
      const int r = wn * 64 + n * 16 + lrow;
#pragma unroll
      for (int kk = 0; kk < 2; ++kk)
        bfr[n][kk] = *(const bf16x8*)(sB + r * 64 + kk * 32 + lko);
    }
#pragma unroll
    for (int kk = 0; kk < 2; ++kk)
#pragma unroll
      for (int m = 0; m < 4; ++m)
#pragma unroll
        for (int n = 0; n < 4; ++n)
          acc[m][n] = __builtin_amdgcn_mfma_f32_16x16x32_bf16(
              af[m][kk], bfr[n][kk], acc[m][n], 0, 0, 0);
    __syncthreads();
  }
#pragma unroll
  for (int n = 0; n < 4; ++n) {
    const int col = col0 + wn * 64 + n * 16 + lrow;
    const float bv = bias[col];
#pragma unroll
    for (int m = 0; m < 4; ++m) {
      const int row = row0 + wm * 64 + m * 16 + (lane >> 4) * 4;
      const f32x4 v = acc[m][n];
#pragma unroll
      for (int j = 0; j < 4; ++j)
        C[(size_t)(row + j) * N + col] = v[j] + bv;
    }
  }
}

// ---------------- host launch ----------------

extern "C" void kernel_launch(void* const* d_in, const int* in_sizes, int n_in,
                              void* d_out, int out_size, void* d_ws, size_t ws_size,
                              hipStream_t stream) {
  const float* x      = (const float*)d_in[0];
  const int* pw       = (const int*)d_in[1];     // uint8 widened to int32
  const float* scale  = (const float*)d_in[2];
  const float* zp     = (const float*)d_in[3];
  const float* bias   = (const float*)d_in[4];
  float* out = (float*)d_out;

  const int K = IN_F, N = OUT_F;
  const int M = in_sizes[0] / K;                 // 8192

  const size_t xbytes = (size_t)M * K * 2;       // 64 MiB
  const size_t wbytes = (size_t)N * K * 2;       // 32 MiB

  if (ws_size >= xbytes + wbytes && (M & 255) == 0) {
    unsigned short* Xb = (unsigned short*)d_ws;
    unsigned short* Wb = (unsigned short*)((char*)d_ws + xbytes);
    cvt_x_kernel<<<2048, 256, 0, stream>>>(x, Xb, (long)M * K / 8);
    dequant_w_kernel<<<(OUT_F / 2) * (IN_F / 8) / 256, 256, 0, stream>>>(pw, scale, zp, Wb);
    gemm256_kernel<<<(M / 256) * (N / 256), 512, 0, stream>>>(Xb, Wb, bias, out, M, N, K);
  } else if (ws_size >= xbytes + wbytes) {
    unsigned short* Xb = (unsigned short*)d_ws;
    unsigned short* Wb = (unsigned short*)((char*)d_ws + xbytes);
    cvt_x_kernel<<<2048, 256, 0, stream>>>(x, Xb, (long)M * K / 8);
    dequant_w_kernel<<<(OUT_F / 2) * (IN_F / 8) / 256, 256, 0, stream>>>(pw, scale, zp, Wb);
    gemm_kernel<true><<<(M / 128) * (N / 128), 256, 0, stream>>>(
        Xb, nullptr, Wb, bias, out, M, N, K);
  } else {
    unsigned short* Wb = (unsigned short*)d_ws;  // requires >= 32 MiB ws
    dequant_w_kernel<<<(OUT_F / 2) * (IN_F / 8) / 256, 256, 0, stream>>>(pw, scale, zp, Wb);
    gemm_kernel<false><<<(M / 128) * (N / 128), 256, 0, stream>>>(
        nullptr, x, Wb, bias, out, M, N, K);
  }
}

// Round 8
// 336.184 us; speedup vs baseline: 1.2372x; 1.2372x over previous
//
#include <hip/hip_runtime.h>
#include <stdint.h>

#define IN_F  4096
#define OUT_F 4096

typedef __attribute__((ext_vector_type(8))) short bf16x8;
typedef __attribute__((ext_vector_type(4))) float f32x4;
typedef __attribute__((ext_vector_type(8))) unsigned short u16x8;

__device__ __forceinline__ unsigned short f2bf(float f) {
  union { float f; unsigned int u; } v; v.f = f;
  return (unsigned short)((v.u + 0x7FFFu + ((v.u >> 16) & 1u)) >> 16);
}

__device__ __forceinline__ void gload_lds16(void* lds, const void* g) {
  __builtin_amdgcn_global_load_lds((const __attribute__((address_space(1))) void*)g,
                                   (__attribute__((address_space(3))) void*)lds,
                                   16u, 0, 0u);
}

// ---------------- prep kernels ----------------

__global__ void cvt_x_kernel(const float* __restrict__ x,
                             unsigned short* __restrict__ o, long n8) {
  long i = (long)blockIdx.x * blockDim.x + threadIdx.x;
  long stride = (long)gridDim.x * blockDim.x;
  for (; i < n8; i += stride) {
    const float4* p = (const float4*)(x + i * 8);
    float4 a = p[0], b = p[1];
    u16x8 r;
    r[0] = f2bf(a.x); r[1] = f2bf(a.y); r[2] = f2bf(a.z); r[3] = f2bf(a.w);
    r[4] = f2bf(b.x); r[5] = f2bf(b.y); r[6] = f2bf(b.z); r[7] = f2bf(b.w);
    *(u16x8*)(o + i * 8) = r;
  }
}

// packed_weight arrives as int32 (harness widens uint8 -> int).
__global__ void dequant_w_kernel(const int* __restrict__ pw,
                                 const float* __restrict__ sp,
                                 const float* __restrict__ zpp,
                                 unsigned short* __restrict__ W) {
  const float scale = *sp, zp = *zpp;
  int i = blockIdx.x * blockDim.x + threadIdx.x;
  const int total = (OUT_F / 2) * (IN_F / 8);
  if (i >= total) return;
  int r = i / (IN_F / 8);
  int c = (i - r * (IN_F / 8)) * 8;
  const int* src = pw + (size_t)r * IN_F + c;
  int4 p0 = *(const int4*)(src);
  int4 p1 = *(const int4*)(src + 4);
  int bytes[8] = { p0.x, p0.y, p0.z, p0.w, p1.x, p1.y, p1.z, p1.w };
  u16x8 lo, hi;
#pragma unroll
  for (int j = 0; j < 8; ++j) {
    unsigned int b = (unsigned int)bytes[j] & 0xFFu;
    lo[j] = f2bf(scale * ((float)(b & 15u) - zp));
    hi[j] = f2bf(scale * ((float)(b >> 4) - zp));
  }
  *(u16x8*)(W + (size_t)(2 * r) * IN_F + c) = lo;
  *(u16x8*)(W + (size_t)(2 * r + 1) * IN_F + c) = hi;
}

// ================= 256x256 8-phase GEMM, m201-template port =================
// 512 thr = 8 waves (2m x 4n), wave owns 128x64. BK=64, dbuf 128 KiB LDS,
// 3-bit XOR chunk swizzle (r3-proven, 0 conflicts).
// Per phase: {reads (8 A or 4 B, feed SAME-phase MFMA); stage quarters;
//   SB0; BAR; lgkmcnt(0); SB0; setprio(1); 16 MFMA kk-outer; setprio(0); BAR}
// Reads/phase: P1 A0(T)->a | P2 B1(T)->tau | P3 A1(T)->a | P4 B0(T+1)->tau
//            | P5 A0(T+1)->a | P6 B1(T+1)->sg | P7 A1(T+1)->a | P8 B0(T+2)->sg
// MFMA pairs:  P1(a,sg) P2(a,tau) P3(a,tau) P4(a,sg) P5(a,tau) P6(a,sg)
//              P7(a,sg) P8(a,tau)       [slot liveness verified]
// Stage slots (1-gload 64-row quarters), counts [0,2,2,4,0,2,2,4]:
//   P2: A(T+2)q0,q2 | P3: B(T+2)q0,q1 | P4: B(T+2)q2,q3,A(T+2)q1,q3
//   P6: A(T+3)q0,q2 | P7: B(T+3)q0,q1 | P8: B(T+3)q2,q3,A(T+3)q1,q3
// Every region staged >= 1 barrier+lgkm0 after last read (cross-wave WAR ok).
// vmcnt(4) at P4/P8 start ONLY (enumerated: drains exactly the needed tile).

#define BAR()   __builtin_amdgcn_s_barrier()
#define SB0()   __builtin_amdgcn_sched_barrier(0)
#define VM(n)   asm volatile("s_waitcnt vmcnt(" #n ")")
#define LGKM0() asm volatile("s_waitcnt lgkmcnt(0)")

__global__ __launch_bounds__(512, 2)
void gemm256_kernel(const unsigned short* __restrict__ A,
                    const unsigned short* __restrict__ B,
                    const float* __restrict__ bias,
                    float* __restrict__ C, int M, int N, int K)
{
  __shared__ unsigned short sA[2 * 16384];   // [buf][256 rows][64] swizzled
  __shared__ unsigned short sB[2 * 16384];

  const int tid  = threadIdx.x;
  const int lane = tid & 63;
  const int wid  = tid >> 6;          // 0..7
  const int wm   = wid >> 2;          // 0..1
  const int wn   = wid & 3;           // 0..3

  // T1: XCD-aware bijective swizzle (grid = 512 = 8*64)
  const int cpx = gridDim.x >> 3;
  const int swz = ((int)blockIdx.x & 7) * cpx + ((int)blockIdx.x >> 3);
  const int ntn = N >> 8;
  const int tm = swz / ntn, tn = swz - tm * ntn;
  const int row0 = tm << 8, col0 = tn << 8;

  const int lrow = lane & 15;
  const int ko4  = lane >> 4;               // 0..3
  const int x7   = lrow & 7;
  const int cK0  = ((ko4 ^ x7) << 3);       // swizzled chunk offset, kk=0
  const int cK1  = (((4 + ko4) ^ x7) << 3); // kk=1

  // staging source pre-swizzle (involution with read-side XOR)
  const int srow   = tid >> 3;              // 0..63 within a 64-row quarter
  const int schunk = (tid & 7) ^ (srow & 7);

  f32x4 acc[8][4];
#pragma unroll
  for (int m = 0; m < 8; ++m)
#pragma unroll
    for (int n = 0; n < 4; ++n)
#pragma unroll
      for (int j = 0; j < 4; ++j) acc[m][n][j] = 0.0f;

  bf16x8 a[4][2];                 // single A slot [m2][kk]
  bf16x8 sg[2][2], tau[2][2];     // two B slots [n2][kk]

  // one 8 KiB quarter (64 rows x 64 cols) per gload
#define STAGE1(arr, buf, q, gbase, kt) \
    gload_lds16(arr + (buf)*16384 + (q)*4096 + wid*512, \
        (gbase) + (size_t)((q)*64 + srow) * K + (kt)*64 + schunk*8)

#define LDA_(buf, mh) do {                                                    \
    _Pragma("unroll")                                                         \
    for (int m2 = 0; m2 < 4; ++m2) {                                          \
      const int off_ = (buf)*16384 + (wm*128 + (mh)*64 + m2*16 + lrow)*64;    \
      a[m2][0] = *(const bf16x8*)(sA + off_ + cK0);                           \
      a[m2][1] = *(const bf16x8*)(sA + off_ + cK1);                           \
    } } while (0)

#define LDB_(dst, buf, nh) do {                                               \
    _Pragma("unroll")                                                         \
    for (int n2 = 0; n2 < 2; ++n2) {                                          \
      const int off_ = (buf)*16384 + (wn*64 + (nh)*32 + n2*16 + lrow)*64;     \
      dst[n2][0] = *(const bf16x8*)(sB + off_ + cK0);                         \
      dst[n2][1] = *(const bf16x8*)(sB + off_ + cK1);                         \
    } } while (0)

  // 16 MFMA, kk-outer (dependent acc pairs distance-8)
#define MFMA_Q(bsrc, NH) do {                                                 \
    __builtin_amdgcn_s_setprio(1);                                            \
    _Pragma("unroll")                                                         \
    for (int kk = 0; kk < 2; ++kk)                                            \
      _Pragma("unroll")                                                       \
      for (int m2 = 0; m2 < 4; ++m2)                                          \
        _Pragma("unroll")                                                     \
        for (int n2 = 0; n2 < 2; ++n2)                                        \
          acc[m2 + 4*0][(NH)*2+n2] = acc[m2][(NH)*2+n2],                      \
          acc[m2][(NH)*2+n2] = acc[m2][(NH)*2+n2];                            \
    __builtin_amdgcn_s_setprio(0);                                            \
  } while (0)
#undef MFMA_Q
#define MFMA_MH(MH, bsrc, NH) do {                                            \
    __builtin_amdgcn_s_setprio(1);                                            \
    _Pragma("unroll")                                                         \
    for (int kk = 0; kk < 2; ++kk)                                            \
      _Pragma("unroll")                                                       \
      for (int m2 = 0; m2 < 4; ++m2)                                          \
        _Pragma("unroll")                                                     \
        for (int n2 = 0; n2 < 2; ++n2)                                        \
          acc[(MH)*4+m2][(NH)*2+n2] = __builtin_amdgcn_mfma_f32_16x16x32_bf16(\
              a[m2][kk], bsrc[n2][kk], acc[(MH)*4+m2][(NH)*2+n2], 0, 0, 0);   \
    __builtin_amdgcn_s_setprio(0);                                            \
  } while (0)

  const unsigned short* Ag = A + (size_t)row0 * K;
  const unsigned short* Bg = B + (size_t)col0 * K;

  // ---- prologue: tile0 (8) then tile1 (8); VM(8) -> tile0 landed ----
  STAGE1(sA, 0, 0, Ag, 0); STAGE1(sA, 0, 2, Ag, 0);
  STAGE1(sB, 0, 0, Bg, 0); STAGE1(sB, 0, 1, Bg, 0);
  STAGE1(sB, 0, 2, Bg, 0); STAGE1(sB, 0, 3, Bg, 0);
  STAGE1(sA, 0, 1, Ag, 0); STAGE1(sA, 0, 3, Ag, 0);
  STAGE1(sA, 1, 0, Ag, 1); STAGE1(sA, 1, 2, Ag, 1);
  STAGE1(sB, 1, 0, Bg, 1); STAGE1(sB, 1, 1, Bg, 1);
  STAGE1(sB, 1, 2, Bg, 1); STAGE1(sB, 1, 3, Bg, 1);
  STAGE1(sA, 1, 1, Ag, 1); STAGE1(sA, 1, 3, Ag, 1);
  SB0(); VM(8); SB0();
  BAR();
  LDB_(sg, 0, 0);           // B0(0) -> sg
  LGKM0(); SB0();
  BAR();

  const int nkt = K >> 6;               // 64 K-tiles
  const int nit = nkt >> 1;             // 32 iterations
  for (int it = 0; it < nit; ++it) {
    const int T   = 2 * it;
    const int k2 = (T + 2 < nkt) ? T + 2 : nkt - 1;  // clamped stages land in
    const int k3 = (T + 3 < nkt) ? T + 3 : nkt - 1;  // regions w/ no live reader
    // P1: read A0(T); MFMA(a, sg=B0(T))
    LDA_(0, 0);
    SB0(); BAR(); LGKM0(); SB0();
    MFMA_MH(0, sg, 0);
    BAR();
    // P2: read B1(T)->tau; stage A(T+2)q0,q2; MFMA(a, tau)
    LDB_(tau, 0, 1);
    STAGE1(sA, 0, 0, Ag, k2); STAGE1(sA, 0, 2, Ag, k2);
    SB0(); BAR(); LGKM0(); SB0();
    MFMA_MH(0, tau, 1);
    BAR();
    // P3: read A1(T); stage B(T+2)q0,q1; MFMA(a, tau=B1(T))
    LDA_(0, 1);
    STAGE1(sB, 0, 0, Bg, k2); STAGE1(sB, 0, 1, Bg, k2);
    SB0(); BAR(); LGKM0(); SB0();
    MFMA_MH(1, tau, 1);
    BAR();
    // P4: VM(4); read B0(T+1)->tau; stage B(T+2)q2,q3 + A(T+2)q1,q3;
    //     MFMA(a, sg=B0(T))
    VM(4); SB0();
    LDB_(tau, 1, 0);
    STAGE1(sB, 0, 2, Bg, k2); STAGE1(sB, 0, 3, Bg, k2);
    STAGE1(sA, 0, 1, Ag, k2); STAGE1(sA, 0, 3, Ag, k2);
    SB0(); BAR(); LGKM0(); SB0();
    MFMA_MH(1, sg, 0);
    BAR();
    // P5: read A0(T+1); MFMA(a, tau=B0(T+1))
    LDA_(1, 0);
    SB0(); BAR(); LGKM0(); SB0();
    MFMA_MH(0, tau, 0);
    BAR();
    // P6: read B1(T+1)->sg; stage A(T+3)q0,q2; MFMA(a, sg)
    LDB_(sg, 1, 1);
    STAGE1(sA, 1, 0, Ag, k3); STAGE1(sA, 1, 2, Ag, k3);
    SB0(); BAR(); LGKM0(); SB0();
    MFMA_MH(0, sg, 1);
    BAR();
    // P7: read A1(T+1); stage B(T+3)q0,q1; MFMA(a, sg=B1(T+1))
    LDA_(1, 1);
    STAGE1(sB, 1, 0, Bg, k3); STAGE1(sB, 1, 1, Bg, k3);
    SB0(); BAR(); LGKM0(); SB0();
    MFMA_MH(1, sg, 1);
    BAR();
    // P8: VM(4); read B0(T+2)->sg; stage B(T+3)q2,q3 + A(T+3)q1,q3;
    //     MFMA(a, tau=B0(T+1))
    VM(4); SB0();
    LDB_(sg, 0, 0);
    STAGE1(sB, 1, 2, Bg, k3); STAGE1(sB, 1, 3, Bg, k3);
    STAGE1(sA, 1, 1, Ag, k3); STAGE1(sA, 1, 3, Ag, k3);
    SB0(); BAR(); LGKM0(); SB0();
    MFMA_MH(1, tau, 0);
    BAR();
  }

  asm volatile("s_waitcnt vmcnt(0)" ::: "memory");  // drain trailing stages

  // ---- epilogue ----
#pragma unroll
  for (int n = 0; n < 4; ++n) {
    const int col = col0 + wn * 64 + n * 16 + lrow;
    const float bv = bias[col];
#pragma unroll
    for (int m = 0; m < 8; ++m) {
      const int row = row0 + wm * 128 + m * 16 + ko4 * 4;
      const f32x4 v = acc[m][n];
#pragma unroll
      for (int j = 0; j < 4; ++j)
        C[(size_t)(row + j) * N + col] = v[j] + bv;
    }
  }
#undef STAGE1
#undef LDA_
#undef LDB_
#undef MFMA_MH
}

// ---------------- fallback 128x128 GEMM (correctness safety net) ----------

template <bool XB16>
__global__ __launch_bounds__(256)
void gemm_kernel(const unsigned short* __restrict__ Abf,
                 const float* __restrict__ Af32,
                 const unsigned short* __restrict__ Bbf,
                 const float* __restrict__ bias,
                 float* __restrict__ C, int M, int N, int K)
{
  __shared__ unsigned short sA[128 * 64];
  __shared__ unsigned short sB[128 * 64];
  const int tid  = threadIdx.x;
  const int lane = tid & 63;
  const int wid  = tid >> 6;
  const int wm = wid >> 1, wn = wid & 1;
  const int ntn = N / 128;
  const int tm = blockIdx.x / ntn, tn = blockIdx.x - tm * ntn;
  const int row0 = tm * 128, col0 = tn * 128;

  f32x4 acc[4][4];
#pragma unroll
  for (int m = 0; m < 4; ++m)
#pragma unroll
    for (int n = 0; n < 4; ++n)
#pragma unroll
      for (int j = 0; j < 4; ++j) acc[m][n][j] = 0.0f;

  const int lrow = lane & 15;
  const int lko  = (lane >> 4) * 8;

  for (int k0 = 0; k0 < K; k0 += 64) {
    if (XB16) {
#pragma unroll
      for (int i = 0; i < 4; ++i) {
        const int wbase = i * 256 + (wid << 6);
        const int c = wbase + lane;
        const int r = c >> 3, ce = (c & 7) * 8;
        gload_lds16(sA + (size_t)wbase * 8, Abf + (size_t)(row0 + r) * K + k0 + ce);
      }
    } else {
#pragma unroll
      for (int i = 0; i < 4; ++i) {
        const int c = i * 256 + tid;
        const int r = c >> 3, ce = (c & 7) * 8;
        const float4* p = (const float4*)(Af32 + (size_t)(row0 + r) * K + k0 + ce);
        float4 aa = p[0], bb = p[1];
        u16x8 v;
        v[0] = f2bf(aa.x); v[1] = f2bf(aa.y); v[2] = f2bf(aa.z); v[3] = f2bf(aa.w);
        v[4] = f2bf(bb.x); v[5] = f2bf(bb.y); v[6] = f2bf(bb.z); v[7] = f2bf(bb.w);
        *(u16x8*)(sA + c * 8) = v;
      }
    }
#pragma unroll
    for (int i = 0; i < 4; ++i) {
      const int wbase = i * 256 + (wid << 6);
      const int c = wbase + lane;
      const int r = c >> 3, ce = (c & 7) * 8;
      gload_lds16(sB + (size_t)wbase * 8, Bbf + (size_t)(col0 + r) * K + k0 + ce);
    }
    __syncthreads();
    bf16x8 af[4][2], bfr[4][2];
#pragma unroll
    for (int m = 0; m < 4; ++m) {
      const int r = wm * 64 + m * 16 + lrow;
#pragma unroll
      for (int kk = 0; kk < 2; ++kk)
        af[m][kk] = *(const bf16x8*)(sA + r * 64 + kk * 32 + lko);
    }
#pragma unroll
    for (int n = 0; n < 4; ++n) {
      const int r = wn * 64 + n * 16 + lrow;
#pragma unroll
      for (int kk = 0; kk < 2; ++kk)
        bfr[n][kk] = *(const bf16x8*)(sB + r * 64 + kk * 32 + lko);
    }
#pragma unroll
    for (int kk = 0; kk < 2; ++kk)
#pragma unroll
      for (int m = 0; m < 4; ++m)
#pragma unroll
        for (int n = 0; n < 4; ++n)
          acc[m][n] = __builtin_amdgcn_mfma_f32_16x16x32_bf16(
              af[m][kk], bfr[n][kk], acc[m][n], 0, 0, 0);
    __syncthreads();
  }
#pragma unroll
  for (int n = 0; n < 4; ++n) {
    const int col = col0 + wn * 64 + n * 16 + lrow;
    const float bv = bias[col];
#pragma unroll
    for (int m = 0; m < 4; ++m) {
      const int row = row0 + wm * 64 + m * 16 + (lane >> 4) * 4;
      const f32x4 v = acc[m][n];
#pragma unroll
      for (int j = 0; j < 4; ++j)
        C[(size_t)(row + j) * N + col] = v[j] + bv;
    }
  }
}

// ---------------- host launch ----------------

extern "C" void kernel_launch(void* const* d_in, const int* in_sizes, int n_in,
                              void* d_out, int out_size, void* d_ws, size_t ws_size,
                              hipStream_t stream) {
  const float* x      = (const float*)d_in[0];
  const int* pw       = (const int*)d_in[1];     // uint8 widened to int32
  const float* scale  = (const float*)d_in[2];
  const float* zp     = (const float*)d_in[3];
  const float* bias   = (const float*)d_in[4];
  float* out = (float*)d_out;

  const int K = IN_F, N = OUT_F;
  const int M = in_sizes[0] / K;                 // 8192

  const size_t xbytes = (size_t)M * K * 2;       // 64 MiB
  const size_t wbytes = (size_t)N * K * 2;       // 32 MiB

  if (ws_size >= xbytes + wbytes && (M & 255) == 0) {
    unsigned short* Xb = (unsigned short*)d_ws;
    unsigned short* Wb = (unsigned short*)((char*)d_ws + xbytes);
    cvt_x_kernel<<<2048, 256, 0, stream>>>(x, Xb, (long)M * K / 8);
    dequant_w_kernel<<<(OUT_F / 2) * (IN_F / 8) / 256, 256, 0, stream>>>(pw, scale, zp, Wb);
    gemm256_kernel<<<(M / 256) * (N / 256), 512, 0, stream>>>(Xb, Wb, bias, out, M, N, K);
  } else if (ws_size >= xbytes + wbytes) {
    unsigned short* Xb = (unsigned short*)d_ws;
    unsigned short* Wb = (unsigned short*)((char*)d_ws + xbytes);
    cvt_x_kernel<<<2048, 256, 0, stream>>>(x, Xb, (long)M * K / 8);
    dequant_w_kernel<<<(OUT_F / 2) * (IN_F / 8) / 256, 256, 0, stream>>>(pw, scale, zp, Wb);
    gemm_kernel<true><<<(M / 128) * (N / 128), 256, 0, stream>>>(
        Xb, nullptr, Wb, bias, out, M, N, K);
  } else {
    unsigned short* Wb = (unsigned short*)d_ws;  // requires >= 32 MiB ws
    dequant_w_kernel<<<(OUT_F / 2) * (IN_F / 8) / 256, 256, 0, stream>>>(pw, scale, zp, Wb);
    gemm_kernel<false><<<(M / 128) * (N / 128), 256, 0, stream>>>(
        nullptr, x, Wb, bias, out, M, N, K);
  }
}

// Round 9
// 324.880 us; speedup vs baseline: 1.2802x; 1.0348x over previous
//
#include <hip/hip_runtime.h>
#include <stdint.h>

#define IN_F  4096
#define OUT_F 4096

typedef __attribute__((ext_vector_type(8))) short bf16x8;
typedef __attribute__((ext_vector_type(4))) float f32x4;
typedef __attribute__((ext_vector_type(8))) unsigned short u16x8;

__device__ __forceinline__ unsigned short f2bf(float f) {
  union { float f; unsigned int u; } v; v.f = f;
  return (unsigned short)((v.u + 0x7FFFu + ((v.u >> 16) & 1u)) >> 16);
}

__device__ __forceinline__ void gload_lds16(void* lds, const void* g) {
  __builtin_amdgcn_global_load_lds((const __attribute__((address_space(1))) void*)g,
                                   (__attribute__((address_space(3))) void*)lds,
                                   16u, 0, 0u);
}

// ---------------- prep kernels ----------------

__global__ void cvt_x_kernel(const float* __restrict__ x,
                             unsigned short* __restrict__ o, long n8) {
  long i = (long)blockIdx.x * blockDim.x + threadIdx.x;
  long stride = (long)gridDim.x * blockDim.x;
  for (; i < n8; i += stride) {
    const float4* p = (const float4*)(x + i * 8);
    float4 a = p[0], b = p[1];
    u16x8 r;
    r[0] = f2bf(a.x); r[1] = f2bf(a.y); r[2] = f2bf(a.z); r[3] = f2bf(a.w);
    r[4] = f2bf(b.x); r[5] = f2bf(b.y); r[6] = f2bf(b.z); r[7] = f2bf(b.w);
    *(u16x8*)(o + i * 8) = r;
  }
}

// packed_weight arrives as int32 (harness widens uint8 -> int).
__global__ void dequant_w_kernel(const int* __restrict__ pw,
                                 const float* __restrict__ sp,
                                 const float* __restrict__ zpp,
                                 unsigned short* __restrict__ W) {
  const float scale = *sp, zp = *zpp;
  int i = blockIdx.x * blockDim.x + threadIdx.x;
  const int total = (OUT_F / 2) * (IN_F / 8);
  if (i >= total) return;
  int r = i / (IN_F / 8);
  int c = (i - r * (IN_F / 8)) * 8;
  const int* src = pw + (size_t)r * IN_F + c;
  int4 p0 = *(const int4*)(src);
  int4 p1 = *(const int4*)(src + 4);
  int bytes[8] = { p0.x, p0.y, p0.z, p0.w, p1.x, p1.y, p1.z, p1.w };
  u16x8 lo, hi;
#pragma unroll
  for (int j = 0; j < 8; ++j) {
    unsigned int b = (unsigned int)bytes[j] & 0xFFu;
    lo[j] = f2bf(scale * ((float)(b & 15u) - zp));
    hi[j] = f2bf(scale * ((float)(b >> 4) - zp));
  }
  *(u16x8*)(W + (size_t)(2 * r) * IN_F + c) = lo;
  *(u16x8*)(W + (size_t)(2 * r + 1) * IN_F + c) = hi;
}

// ========== 256x256 8-phase GEMM: Gray-code rotation, reads 1 phase ahead ===
// 512 thr = 8 waves (2m x 4n), wave owns 128x64. BK=64, dbuf 128 KiB LDS,
// 3-bit XOR chunk swizzle (0 conflicts, proven r3/r8).
// Quadrants per tile: Q1(A0,B0) Q2(A0,B1) Q3(A1,B1) Q4(A1,B0). Every operand
// ds_read ONE phase before first use -> LDS service overlaps MFMA; NO
// explicit lgkmcnt(0) (compiler emits counted waits). Per-phase ds-read dest
// slot is never the same phase's MFMA operand (verified):
//   ph : read->slot        MFMA(a,b)   stages (tile kt2->buf0, kt3->buf1)
//   P1 : B1[T]  ->U        (Y,V)       A q0,q2 buf0
//   P2 : A1[T]  ->X        (Y,U)       --
//   P3 : A0[T+1]->Y        (X,U)       B q0,q1 buf0
//   P4 : B0[T+1]->U        (X,V)       B q2,q3 buf0
//   P5 : B1[T+1]->V        (Y,U)       A q1,q3 buf0
//   P6 : A1[T+1]->X        (Y,V)       A q0,q2 buf1
//   P7 : A0[T+2]->Y        (X,V)       B q0,q1 buf1
//   P8 : B0[T+2]->V        (X,U)       B q2,q3 + A q1,q3 buf1
// Cross-wave rule enforced: every read depends only on stages drained by a
// VM at <= phase-1 followed by a barrier. VM = [8,8,2,-,-,6,4,-] (FIFO replay
// verified incl. prologue VM(14)/VM(10)). Tail clamps idempotent/dead.

#define BAR()   __builtin_amdgcn_s_barrier()
#define SB0()   __builtin_amdgcn_sched_barrier(0)
#define VM(n)   asm volatile("s_waitcnt vmcnt(" #n ")")

__global__ __launch_bounds__(512, 2)
void gemm256_kernel(const unsigned short* __restrict__ A,
                    const unsigned short* __restrict__ B,
                    const float* __restrict__ bias,
                    float* __restrict__ C, int M, int N, int K)
{
  __shared__ unsigned short sA[2 * 16384];   // [buf][256 rows][64] swizzled
  __shared__ unsigned short sB[2 * 16384];

  const int tid  = threadIdx.x;
  const int lane = tid & 63;
  const int wid  = tid >> 6;          // 0..7
  const int wm   = wid >> 2;          // 0..1
  const int wn   = wid & 3;           // 0..3

  // T1: XCD-aware bijective swizzle (grid = 512 = 8*64)
  const int cpx = gridDim.x >> 3;
  const int swz = ((int)blockIdx.x & 7) * cpx + ((int)blockIdx.x >> 3);
  const int ntn = N >> 8;
  const int tm = swz / ntn, tn = swz - tm * ntn;
  const int row0 = tm << 8, col0 = tn << 8;

  const int lrow = lane & 15;
  const int ko4  = lane >> 4;               // 0..3
  const int x7   = lrow & 7;
  const int cK0  = ((ko4 ^ x7) << 3);       // swizzled chunk offset, kk=0
  const int cK1  = (((4 + ko4) ^ x7) << 3); // kk=1

  // staging source pre-swizzle (involution with read-side XOR)
  const int srow   = tid >> 3;              // 0..63 within a 64-row quarter
  const int schunk = (tid & 7) ^ (srow & 7);

  f32x4 acc[8][4];
#pragma unroll
  for (int m = 0; m < 8; ++m)
#pragma unroll
    for (int n = 0; n < 4; ++n)
#pragma unroll
      for (int j = 0; j < 4; ++j) acc[m][n][j] = 0.0f;

  bf16x8 X[4][2], Y[4][2];        // A slots [m2][kk]
  bf16x8 U[2][2], V[2][2];        // B slots [n2][kk]

  // one 8 KiB quarter (64 rows x 64 cols) per gload
#define STAGE1(arr, buf, q, gbase, kt) \
    gload_lds16(arr + (buf)*16384 + (q)*4096 + wid*512, \
        (gbase) + (size_t)((q)*64 + srow) * K + (kt)*64 + schunk*8)

#define LDA_(dst, buf, mh) do {                                               \
    _Pragma("unroll")                                                         \
    for (int m2 = 0; m2 < 4; ++m2) {                                          \
      const int off_ = (buf)*16384 + (wm*128 + (mh)*64 + m2*16 + lrow)*64;    \
      dst[m2][0] = *(const bf16x8*)(sA + off_ + cK0);                         \
      dst[m2][1] = *(const bf16x8*)(sA + off_ + cK1);                         \
    } } while (0)

#define LDB_(dst, buf, nh) do {                                               \
    _Pragma("unroll")                                                         \
    for (int n2 = 0; n2 < 2; ++n2) {                                          \
      const int off_ = (buf)*16384 + (wn*64 + (nh)*32 + n2*16 + lrow)*64;     \
      dst[n2][0] = *(const bf16x8*)(sB + off_ + cK0);                         \
      dst[n2][1] = *(const bf16x8*)(sB + off_ + cK1);                         \
    } } while (0)

  // 16 MFMA, kk-outer (dependent acc pairs distance-8)
#define MFMA_Q(asrc, bsrc, MH, NH) do {                                       \
    __builtin_amdgcn_s_setprio(1);                                            \
    _Pragma("unroll")                                                         \
    for (int kk = 0; kk < 2; ++kk)                                            \
      _Pragma("unroll")                                                       \
      for (int m2 = 0; m2 < 4; ++m2)                                          \
        _Pragma("unroll")                                                     \
        for (int n2 = 0; n2 < 2; ++n2)                                        \
          acc[(MH)*4+m2][(NH)*2+n2] = __builtin_amdgcn_mfma_f32_16x16x32_bf16(\
              asrc[m2][kk], bsrc[n2][kk], acc[(MH)*4+m2][(NH)*2+n2], 0,0,0);  \
    __builtin_amdgcn_s_setprio(0);                                            \
  } while (0)

  const unsigned short* Ag = A + (size_t)row0 * K;
  const unsigned short* Bg = B + (size_t)col0 * K;

  // ---- prologue: 16 stages in steady slot order (virtual prev iteration) --
  STAGE1(sA, 0, 0, Ag, 0); STAGE1(sA, 0, 2, Ag, 0);   // S1: A q0,q2 buf0
  STAGE1(sB, 0, 0, Bg, 0); STAGE1(sB, 0, 1, Bg, 0);   // S3: B q0,q1 buf0
  STAGE1(sB, 0, 2, Bg, 0); STAGE1(sB, 0, 3, Bg, 0);   // S4: B q2,q3 buf0
  STAGE1(sA, 0, 1, Ag, 0); STAGE1(sA, 0, 3, Ag, 0);   // S5: A q1,q3 buf0
  STAGE1(sA, 1, 0, Ag, 1); STAGE1(sA, 1, 2, Ag, 1);   // S6: A q0,q2 buf1
  STAGE1(sB, 1, 0, Bg, 1); STAGE1(sB, 1, 1, Bg, 1);   // S7: B q0,q1 buf1
  STAGE1(sB, 1, 2, Bg, 1); STAGE1(sB, 1, 3, Bg, 1);   // S8a: B q2,q3 buf1
  STAGE1(sA, 1, 1, Ag, 1); STAGE1(sA, 1, 3, Ag, 1);   // S8b: A q1,q3 buf1
  SB0(); VM(14); SB0();      // S1 landed
  BAR();
  LDA_(Y, 0, 0);             // A0[0] -> Y
  SB0(); VM(10); SB0();      // S3,S4 landed
  BAR();
  LDB_(V, 0, 0);             // B0[0] -> V
  SB0();

  const int nkt = K >> 6;               // 64 K-tiles
  const int nit = nkt >> 1;             // 32 iterations
  for (int it = 0; it < nit; ++it) {
    const int T   = 2 * it;
    const int kt2 = (T + 2 < nkt) ? T + 2 : nkt - 1;  // clamp: idempotent or
    const int kt3 = (T + 3 < nkt) ? T + 3 : nkt - 1;  // dead-register regions
    // P1: read B1[T]->U; stage A q0,q2 buf0[kt2]; MFMA(Y,V)=Q1[T]
    VM(8); SB0();
    LDB_(U, 0, 1);
    STAGE1(sA, 0, 0, Ag, kt2); STAGE1(sA, 0, 2, Ag, kt2);
    SB0(); BAR();
    MFMA_Q(Y, V, 0, 0);
    BAR(); SB0();
    // P2: read A1[T]->X; MFMA(Y,U)=Q2[T]
    VM(8); SB0();
    LDA_(X, 0, 1);
    SB0(); BAR();
    MFMA_Q(Y, U, 0, 1);
    BAR(); SB0();
    // P3: read A0[T+1]->Y; stage B q0,q1 buf0[kt2]; MFMA(X,U)=Q3[T]
    VM(2); SB0();
    LDA_(Y, 1, 0);
    STAGE1(sB, 0, 0, Bg, kt2); STAGE1(sB, 0, 1, Bg, kt2);
    SB0(); BAR();
    MFMA_Q(X, U, 1, 1);
    BAR(); SB0();
    // P4: read B0[T+1]->U; stage B q2,q3 buf0[kt2]; MFMA(X,V)=Q4[T]
    LDB_(U, 1, 0);
    STAGE1(sB, 0, 2, Bg, kt2); STAGE1(sB, 0, 3, Bg, kt2);
    SB0(); BAR();
    MFMA_Q(X, V, 1, 0);
    BAR(); SB0();
    // P5: read B1[T+1]->V; stage A q1,q3 buf0[kt2]; MFMA(Y,U)=Q1[T+1]
    LDB_(V, 1, 1);
    STAGE1(sA, 0, 1, Ag, kt2); STAGE1(sA, 0, 3, Ag, kt2);
    SB0(); BAR();
    MFMA_Q(Y, U, 0, 0);
    BAR(); SB0();
    // P6: read A1[T+1]->X; stage A q0,q2 buf1[kt3]; MFMA(Y,V)=Q2[T+1]
    VM(6); SB0();
    LDA_(X, 1, 1);
    STAGE1(sA, 1, 0, Ag, kt3); STAGE1(sA, 1, 2, Ag, kt3);
    SB0(); BAR();
    MFMA_Q(Y, V, 0, 1);
    BAR(); SB0();
    // P7: read A0[T+2]->Y; stage B q0,q1 buf1[kt3]; MFMA(X,V)=Q3[T+1]
    VM(4); SB0();
    LDA_(Y, 0, 0);
    STAGE1(sB, 1, 0, Bg, kt3); STAGE1(sB, 1, 1, Bg, kt3);
    SB0(); BAR();
    MFMA_Q(X, V, 1, 1);
    BAR(); SB0();
    // P8: read B0[T+2]->V; stage B q2,q3 + A q1,q3 buf1[kt3]; MFMA(X,U)=Q4[T+1]
    LDB_(V, 0, 0);
    STAGE1(sB, 1, 2, Bg, kt3); STAGE1(sB, 1, 3, Bg, kt3);
    STAGE1(sA, 1, 1, Ag, kt3); STAGE1(sA, 1, 3, Ag, kt3);
    SB0(); BAR();
    MFMA_Q(X, U, 1, 0);
    BAR(); SB0();
  }

  asm volatile("s_waitcnt vmcnt(0)" ::: "memory");  // drain trailing stages

  // ---- epilogue ----
#pragma unroll
  for (int n = 0; n < 4; ++n) {
    const int col = col0 + wn * 64 + n * 16 + lrow;
    const float bv = bias[col];
#pragma unroll
    for (int m = 0; m < 8; ++m) {
      const int row = row0 + wm * 128 + m * 16 + ko4 * 4;
      const f32x4 v = acc[m][n];
#pragma unroll
      for (int j = 0; j < 4; ++j)
        C[(size_t)(row + j) * N + col] = v[j] + bv;
    }
  }
#undef STAGE1
#undef LDA_
#undef LDB_
#undef MFMA_Q
}

// ---------------- fallback 128x128 GEMM (correctness safety net) ----------

template <bool XB16>
__global__ __launch_bounds__(256)
void gemm_kernel(const unsigned short* __restrict__ Abf,
                 const float* __restrict__ Af32,
                 const unsigned short* __restrict__ Bbf,
                 const float* __restrict__ bias,
                 float* __restrict__ C, int M, int N, int K)
{
  __shared__ unsigned short sA[128 * 64];
  __shared__ unsigned short sB[128 * 64];
  const int tid  = threadIdx.x;
  const int lane = tid & 63;
  const int wid  = tid >> 6;
  const int wm = wid >> 1, wn = wid & 1;
  const int ntn = N / 128;
  const int tm = blockIdx.x / ntn, tn = blockIdx.x - tm * ntn;
  const int row0 = tm * 128, col0 = tn * 128;

  f32x4 acc[4][4];
#pragma unroll
  for (int m = 0; m < 4; ++m)
#pragma unroll
    for (int n = 0; n < 4; ++n)
#pragma unroll
      for (int j = 0; j < 4; ++j) acc[m][n][j] = 0.0f;

  const int lrow = lane & 15;
  const int lko  = (lane >> 4) * 8;

  for (int k0 = 0; k0 < K; k0 += 64) {
    if (XB16) {
#pragma unroll
      for (int i = 0; i < 4; ++i) {
        const int wbase = i * 256 + (wid << 6);
        const int c = wbase + lane;
        const int r = c >> 3, ce = (c & 7) * 8;
        gload_lds16(sA + (size_t)wbase * 8, Abf + (size_t)(row0 + r) * K + k0 + ce);
      }
    } else {
#pragma unroll
      for (int i = 0; i < 4; ++i) {
        const int c = i * 256 + tid;
        const int r = c >> 3, ce = (c & 7) * 8;
        const float4* p = (const float4*)(Af32 + (size_t)(row0 + r) * K + k0 + ce);
        float4 aa = p[0], bb = p[1];
        u16x8 v;
        v[0] = f2bf(aa.x); v[1] = f2bf(aa.y); v[2] = f2bf(aa.z); v[3] = f2bf(aa.w);
        v[4] = f2bf(bb.x); v[5] = f2bf(bb.y); v[6] = f2bf(bb.z); v[7] = f2bf(bb.w);
        *(u16x8*)(sA + c * 8) = v;
      }
    }
#pragma unroll
    for (int i = 0; i < 4; ++i) {
      const int wbase = i * 256 + (wid << 6);
      const int c = wbase + lane;
      const int r = c >> 3, ce = (c & 7) * 8;
      gload_lds16(sB + (size_t)wbase * 8, Bbf + (size_t)(col0 + r) * K + k0 + ce);
    }
    __syncthreads();
    bf16x8 af[4][2], bfr[4][2];
#pragma unroll
    for (int m = 0; m < 4; ++m) {
      const int r = wm * 64 + m * 16 + lrow;
#pragma unroll
      for (int kk = 0; kk < 2; ++kk)
        af[m][kk] = *(const bf16x8*)(sA + r * 64 + kk * 32 + lko);
    }
#pragma unroll
    for (int n = 0; n < 4; ++n) {
      const int r = wn * 64 + n * 16 + lrow;
#pragma unroll
      for (int kk = 0; kk < 2; ++kk)
        bfr[n][kk] = *(const bf16x8*)(sB + r * 64 + kk * 32 + lko);
    }
#pragma unroll
    for (int kk = 0; kk < 2; ++kk)
#pragma unroll
      for (int m = 0; m < 4; ++m)
#pragma unroll
        for (int n = 0; n < 4; ++n)
          acc[m][n] = __builtin_amdgcn_mfma_f32_16x16x32_bf16(
              af[m][kk], bfr[n][kk], acc[m][n], 0, 0, 0);
    __syncthreads();
  }
#pragma unroll
  for (int n = 0; n < 4; ++n) {
    const int col = col0 + wn * 64 + n * 16 + lrow;
    const float bv = bias[col];
#pragma unroll
    for (int m = 0; m < 4; ++m) {
      const int row = row0 + wm * 64 + m * 16 + (lane >> 4) * 4;
      const f32x4 v = acc[m][n];
#pragma unroll
      for (int j = 0; j < 4; ++j)
        C[(size_t)(row + j) * N + col] = v[j] + bv;
    }
  }
}

// ---------------- host launch ----------------

extern "C" void kernel_launch(void* const* d_in, const int* in_sizes, int n_in,
                              void* d_out, int out_size, void* d_ws, size_t ws_size,
                              hipStream_t stream) {
  const float* x      = (const float*)d_in[0];
  const int* pw       = (const int*)d_in[1];     // uint8 widened to int32
  const float* scale  = (const float*)d_in[2];
  const float* zp     = (const float*)d_in[3];
  const float* bias   = (const float*)d_in[4];
  float* out = (float*)d_out;

  const int K = IN_F, N = OUT_F;
  const int M = in_sizes[0] / K;                 // 8192

  const size_t xbytes = (size_t)M * K * 2;       // 64 MiB
  const size_t wbytes = (size_t)N * K * 2;       // 32 MiB

  if (ws_size >= xbytes + wbytes && (M & 255) == 0) {
    unsigned short* Xb = (unsigned short*)d_ws;
    unsigned short* Wb = (unsigned short*)((char*)d_ws + xbytes);
    cvt_x_kernel<<<2048, 256, 0, stream>>>(x, Xb, (long)M * K / 8);
    dequant_w_kernel<<<(OUT_F / 2) * (IN_F / 8) / 256, 256, 0, stream>>>(pw, scale, zp, Wb);
    gemm256_kernel<<<(M / 256) * (N / 256), 512, 0, stream>>>(Xb, Wb, bias, out, M, N, K);
  } else if (ws_size >= xbytes + wbytes) {
    unsigned short* Xb = (unsigned short*)d_ws;
    unsigned short* Wb = (unsigned short*)((char*)d_ws + xbytes);
    cvt_x_kernel<<<2048, 256, 0, stream>>>(x, Xb, (long)M * K / 8);
    dequant_w_kernel<<<(OUT_F / 2) * (IN_F / 8) / 256, 256, 0, stream>>>(pw, scale, zp, Wb);
    gemm_kernel<true><<<(M / 128) * (N / 128), 256, 0, stream>>>(
        Xb, nullptr, Wb, bias, out, M, N, K);
  } else {
    unsigned short* Wb = (unsigned short*)d_ws;  // requires >= 32 MiB ws
    dequant_w_kernel<<<(OUT_F / 2) * (IN_F / 8) / 256, 256, 0, stream>>>(pw, scale, zp, Wb);
    gemm_kernel<false><<<(M / 128) * (N / 128), 256, 0, stream>>>(
        nullptr, x, Wb, bias, out, M, N, K);
  }
}